// Round 2
// baseline (69.807 us; speedup 1.0000x reference)
//
#include <hip/hip_runtime.h>

#define DD 8
#define LOG2E_HALF 0.7213475204444817f  // 0.5 / ln(2)

// Pair-independent coefficient tables, computed once per launch into d_ws:
//   cf[  0.. 63] : B[c][k]   = 0.5*log2(e) * inv2[c][k]   (exp2 argument matrix)
//   cf[ 64..127] : G[j][c]   = s0*sJ*M[c,j]
//   cf[128..191] : K[j][c]   = s0*sJ*M[c,j]^2
//   cf[192..199] : l2[j]     = L[0,j]^2
//   cf[200..207] : r1[d]     = -4*s0*sd*tl[d]   (diag-correction linear coef)
//   cf[208..215] : r0[d]     =  2*s0*sd         (diag-correction const coef)
__global__ void setup_coeffs(const float* __restrict__ L,
                             const float* __restrict__ sigma,
                             float* __restrict__ cf) {
    int t = threadIdx.x;            // 0..63
    int j = t >> 3;                 // row
    int c = t & 7;                  // col

    // B matrix (exp2 argument coefficients), indexed [c_row][k]
    float Ljc_ = L[j * DD + c];
    cf[j * DD + c] = LOG2E_HALF / (Ljc_ * Ljc_);

    // G/K tables, stored [j][c]
    float s0  = sigma[0];
    float L0j = L[j];                       // L[I0=0][j]
    float l2j = L0j * L0j;
    float sJ  = sigma[j] / (l2j * l2j);
    float L0c = L[c];
    float Ljc = L[j * DD + c];
    float Mcj = 1.0f / (L0c * L0c) + 1.0f / (Ljc * Ljc);   // inv2[0,c] + inv2[j,c]
    float G   = s0 * sJ * Mcj;
    cf[64  + j * DD + c] = G;
    cf[128 + j * DD + c] = G * Mcj;

    if (t < DD) {
        int d = t;
        float L0d = L[d];
        float l2  = L0d * L0d;
        cf[192 + d] = l2;
        float Ldd = L[d * DD + d];
        float tl  = 1.0f / l2 + 1.0f / (Ldd * Ldd);        // inv2[0,d] + inv2[d,d]
        float sd  = sigma[d] / (l2 * l2);
        cf[200 + d] = -4.0f * s0 * sd * tl;                // r1
        cf[208 + d] =  2.0f * s0 * sd;                     // r0
    }
}

__global__ __launch_bounds__(256) void rbf_main(
        const float* __restrict__ x1, const float* __restrict__ x2,
        const float* __restrict__ cf, float* __restrict__ out,
        int N, int M) {
    int m = blockIdx.x * 256 + threadIdx.x;
    int n = blockIdx.y;
    if (m >= M) return;

    // x1 row is block-uniform -> scalar loads; x2 row per-thread vectorized.
    const float* xr = x1 + (size_t)n * DD;
    const float4 ya = *reinterpret_cast<const float4*>(x2 + (size_t)m * DD);
    const float4 yb = *reinterpret_cast<const float4*>(x2 + (size_t)m * DD + 4);
    float yv[DD] = {ya.x, ya.y, ya.z, ya.w, yb.x, yb.y, yb.z, yb.w};

    float dd[DD];
#pragma unroll
    for (int k = 0; k < DD; ++k) {
        float dif = xr[k] - yv[k];
        dd[k] = dif * dif;
    }

    // e[c] = exp(-0.5 * sum_k dd[k]*inv2[c,k]) via exp2 with folded scale
    float e[DD];
#pragma unroll
    for (int c = 0; c < DD; ++c) {
        float A = 0.0f;
#pragma unroll
        for (int k = 0; k < DD; ++k) A = fmaf(dd[k], cf[c * DD + k], A);
        e[c] = exp2f(-A);
    }

    float w[DD];
#pragma unroll
    for (int c = 0; c < DD; ++c) w[c] = dd[c] * e[c];

    float acc = 0.0f;
#pragma unroll
    for (int j = 0; j < DD; ++j) {
        float ge = 0.0f, kw = 0.0f;
#pragma unroll
        for (int c = 0; c < DD; ++c) {
            ge = fmaf(cf[64  + j * DD + c], e[c], ge);
            kw = fmaf(cf[128 + j * DD + c], w[c], kw);
        }
        float fj = (cf[192 + j] - dd[j]) * e[j];
        acc = fmaf(fj, ge - kw, acc);
    }

    // diagonal correction: sum_d (r0[d] + r1[d]*dd[d]) * e[d]^2
#pragma unroll
    for (int d = 0; d < DD; ++d) {
        float adj = fmaf(cf[200 + d], dd[d], cf[208 + d]);
        acc = fmaf(adj * e[d], e[d], acc);
    }

    out[(size_t)n * M + m] = e[0] * acc;   // common e0 factor
}

extern "C" void kernel_launch(void* const* d_in, const int* in_sizes, int n_in,
                              void* d_out, int out_size, void* d_ws, size_t ws_size,
                              hipStream_t stream) {
    const float* x1 = (const float*)d_in[0];
    const float* x2 = (const float*)d_in[1];
    const float* L  = (const float*)d_in[2];
    const float* sg = (const float*)d_in[3];
    float* out = (float*)d_out;
    float* cf  = (float*)d_ws;

    int N = in_sizes[0] / DD;
    int M = in_sizes[1] / DD;

    setup_coeffs<<<1, 64, 0, stream>>>(L, sg, cf);
    dim3 grid((M + 255) / 256, N);
    rbf_main<<<grid, 256, 0, stream>>>(x1, x2, cf, out, N, M);
}